// Round 16
// baseline (2681.439 us; speedup 1.0000x reference)
//
#include <hip/hip_runtime.h>
#include <hip/hip_bf16.h>
#include <math.h>

#define V 50257
#define SQ 1024
#define E 768
#define NH 12
#define NL 12
#define NB 4
#define MR (NB*SQ)   // 4096 rows

typedef __bf16 bf16x8 __attribute__((ext_vector_type(8)));
typedef float f32x4 __attribute__((ext_vector_type(4)));
typedef unsigned short us8 __attribute__((ext_vector_type(8)));

__device__ __forceinline__ float b2f(unsigned short u) {
    union { float f; unsigned int i; } x; x.i = ((unsigned int)u) << 16; return x.f;
}
__device__ __forceinline__ unsigned short f2b(float f) {
    unsigned int u = __float_as_uint(f);
    u = (u + 0x7fff + ((u >> 16) & 1)) >> 16;   // RNE, finite inputs
    return (unsigned short)u;
}
__device__ __forceinline__ void gload16(const unsigned short* g, unsigned short* l) {
    __builtin_amdgcn_global_load_lds((const __attribute__((address_space(1))) void*)g,
                                     (__attribute__((address_space(3))) void*)l, 16, 0, 0);
}

// ---------------- embedding (fp32 out) ----------------
__global__ __launch_bounds__(256)
void embed_k(const int* __restrict__ idx, const float* __restrict__ wte,
             const float* __restrict__ wpe, float* __restrict__ x)
{
    int r = blockIdx.x, t = threadIdx.x;
    int tok = idx[r];
    int s = r & (SQ - 1);
    const float* wt = wte + (size_t)tok * E;
    const float* wp = wpe + (size_t)s * E;
    float* xr = x + (size_t)r * E;
    for (int e = t; e < E; e += 256) xr[e] = wt[e] + wp[e];
}

// ---------------- layernorm: fp32 in, bf16 out (r13 measured-best version) ----------------
__global__ __launch_bounds__(256)
void ln_k(const float* __restrict__ x, const float* __restrict__ g,
          const float* __restrict__ bb, unsigned short* __restrict__ out)
{
    int r = blockIdx.x, t = threadIdx.x;
    int lane = t & 63, wid = t >> 6;
    const float* xr = x + (size_t)r * E;
    float v0 = xr[t], v1 = xr[t + 256], v2 = xr[t + 512];
    float s = v0 + v1 + v2;
    #pragma unroll
    for (int o = 1; o < 64; o <<= 1) s += __shfl_xor(s, o);
    __shared__ float red[8];
    if (lane == 0) red[wid] = s;
    __syncthreads();
    float mu = (red[0] + red[1] + red[2] + red[3]) * (1.f / E);
    float d0 = v0 - mu, d1 = v1 - mu, d2 = v2 - mu;
    float s2 = d0 * d0 + d1 * d1 + d2 * d2;
    #pragma unroll
    for (int o = 1; o < 64; o <<= 1) s2 += __shfl_xor(s2, o);
    if (lane == 0) red[wid + 4] = s2;
    __syncthreads();
    float rs = rsqrtf((red[4] + red[5] + red[6] + red[7]) * (1.f / E) + 1e-5f);
    unsigned short* orow = out + (size_t)r * E;
    orow[t]       = f2b(d0 * rs * g[t] + bb[t]);
    orow[t + 256] = f2b(d1 * rs * g[t + 256] + bb[t + 256]);
    orow[t + 512] = f2b(d2 * rs * g[t + 512] + bb[t + 512]);
}

// ---------------- fp32 -> bf16 elementwise (wte) ----------------
__global__ __launch_bounds__(256)
void conv_k(const float* __restrict__ in, unsigned short* __restrict__ out, int n4)
{
    int i = blockIdx.x * 256 + threadIdx.x;
    int stride = gridDim.x * 256;
    for (; i < n4; i += stride) {
        float4 v = ((const float4*)in)[i];
        ushort4 o;
        o.x = f2b(v.x); o.y = f2b(v.y); o.z = f2b(v.z); o.w = f2b(v.w);
        ((ushort4*)out)[i] = o;
    }
}

// ---------------- transpose+convert: in [Kd,Nd] fp32 -> out [Nd,Kd] bf16 ----------------
__global__ __launch_bounds__(256)
void tconv_k(const float* __restrict__ in, unsigned short* __restrict__ out, int Kd, int Nd)
{
    __shared__ float tile[32][33];
    size_t loff = (size_t)blockIdx.z * Kd * Nd;
    in  += loff;
    out += loff;
    int n0 = blockIdx.x * 32, k0 = blockIdx.y * 32;
    int tc = threadIdx.x & 31, tr = threadIdx.x >> 5;
    #pragma unroll
    for (int i = 0; i < 4; ++i)
        tile[tr + i * 8][tc] = in[(size_t)(k0 + tr + i * 8) * Nd + n0 + tc];
    __syncthreads();
    #pragma unroll
    for (int i = 0; i < 4; ++i)
        out[(size_t)(n0 + tr + i * 8) * Kd + k0 + tc] = f2b(tile[tc][tr + i * 8]);
}

// ---------------- bf16 MFMA GEMM: C = epi(A @ B^T) ----------------
// Per-site configs A/B-measured (r6-r15): single-buffer everywhere.
// 128x128 qkv/fc (keep >=2 blocks/CU resident); 64x128 proj/fcp; 128x256 lm_head only.
// EPI: 0 bias->bf16 (+V-transpose side-write) | 1 bias+resid->fp32 | 2 bias+gelu->bf16
//      | 3 plain->fp32 N-guarded + online-softmax row partials (lm_head)
template<int EPI, bool DB, int MI, int NI, int MINW>
__global__ __launch_bounds__(256, MINW)
void gemm_k(const unsigned short* __restrict__ A, const unsigned short* __restrict__ B,
            const float* __restrict__ bias, const float* __restrict__ resid,
            void* __restrict__ Cv, unsigned short* __restrict__ vt,
            float2* __restrict__ part, int M, int N, int K, int Nreal)
{
    constexpr int NBUF = DB ? 2 : 1;
    constexpr int BM = 32 * MI, BN = 32 * NI;
    __shared__ __align__(16) unsigned short As[NBUF][BM * 64];
    __shared__ __align__(16) unsigned short Bs[NBUF][BN * 64];
    const int t = threadIdx.x;
    const int lane = t & 63, wv = t >> 6;
    const int wr = wv >> 1, wc = wv & 1;
    const int m0 = blockIdx.x * BM, n0 = blockIdx.y * BN;
    const int ntile = blockIdx.y;
    const int lq = lane & 15, lg = lane >> 4;

    f32x4 acc[MI][NI];
    const f32x4 fz = {0.f, 0.f, 0.f, 0.f};
    #pragma unroll
    for (int i = 0; i < MI; ++i)
        #pragma unroll
        for (int j = 0; j < NI; ++j) acc[i][j] = fz;

    const int srow = t >> 3, sc = t & 7;       // staging: 8 lanes/row, 16B chunks

    auto stage = [&](int buf, int k0) {
        #pragma unroll
        for (int i = 0; i < MI; ++i) {
            int row = srow + i * 32;
            int gc = ((sc ^ (row & 7)) << 3);           // pre-swizzled global chunk
            gload16(A + (size_t)(m0 + row) * K + k0 + gc, &As[buf][row * 64 + sc * 8]);
        }
        #pragma unroll
        for (int i = 0; i < NI; ++i) {
            int row = srow + i * 32;
            int gc = ((sc ^ (row & 7)) << 3);
            int nrow = n0 + row;
            if (EPI == 3 && nrow >= Nreal) nrow = Nreal - 1;
            gload16(B + (size_t)nrow * K + k0 + gc, &Bs[buf][row * 64 + sc * 8]);
        }
    };
    auto compute = [&](int buf) {
        #pragma unroll
        for (int ks = 0; ks < 64; ks += 32) {
            bf16x8 af[MI], bfr[NI];
            #pragma unroll
            for (int mi = 0; mi < MI; ++mi) {
                int row = wr * (16 * MI) + mi * 16 + lq;
                int c = (ks >> 3) + lg;
                af[mi] = *(const bf16x8*)&As[buf][row * 64 + ((c ^ (row & 7)) << 3)];
            }
            #pragma unroll
            for (int ni = 0; ni < NI; ++ni) {
                int row = wc * (16 * NI) + ni * 16 + lq;
                int c = (ks >> 3) + lg;
                bfr[ni] = *(const bf16x8*)&Bs[buf][row * 64 + ((c ^ (row & 7)) << 3)];
            }
            #pragma unroll
            for (int mi = 0; mi < MI; ++mi)
                #pragma unroll
                for (int ni = 0; ni < NI; ++ni)
                    acc[mi][ni] = __builtin_amdgcn_mfma_f32_16x16x32_bf16(
                        af[mi], bfr[ni], acc[mi][ni], 0, 0, 0);
        }
    };

    const int KT = K >> 6;
    if constexpr (DB) {
        stage(0, 0);
        __syncthreads();
        int cur = 0;
        for (int kt = 0; kt < KT; ++kt) {
            if (kt + 1 < KT) stage(cur ^ 1, (kt + 1) << 6);   // prefetch next tile
            compute(cur);
            __syncthreads();   // drains next-tile loads (overlapped with MFMA above)
            cur ^= 1;
        }
    } else {
        for (int kt = 0; kt < KT; ++kt) {
            stage(0, kt << 6);
            __syncthreads();
            compute(0);
            __syncthreads();
        }
    }

    // epilogue: D row=4*lg+j (+16mi +wr*16MI), col=lq (+16ni +wc*16NI)
    const int colb = n0 + wc * (16 * NI) + lq;
    const int rowb = m0 + wr * (16 * MI) + lg * 4;

    if constexpr (EPI == 3) {
        __shared__ float2 Ls[2][BM / 2][2];
        float* C = (float*)Cv;
        #pragma unroll
        for (int mi = 0; mi < MI; ++mi) {
            #pragma unroll
            for (int j = 0; j < 4; ++j) {
                int row = rowb + mi * 16 + j;
                float v[NI];
                #pragma unroll
                for (int ni = 0; ni < NI; ++ni) {
                    int col = colb + ni * 16;
                    float vv = acc[mi][ni][j];
                    if (col < Nreal) C[(size_t)row * Nreal + col] = vv;
                    else vv = -1e30f;
                    v[ni] = vv;
                }
                float lm = v[0];
                #pragma unroll
                for (int ni = 1; ni < NI; ++ni) lm = fmaxf(lm, v[ni]);
                #pragma unroll
                for (int o = 1; o < 16; o <<= 1) lm = fmaxf(lm, __shfl_xor(lm, o));
                float ls = 0.f;
                #pragma unroll
                for (int ni = 0; ni < NI; ++ni) ls += __expf(v[ni] - lm);
                #pragma unroll
                for (int o = 1; o < 16; o <<= 1) ls += __shfl_xor(ls, o);
                if (lq == 0) Ls[wr][mi * 16 + lg * 4 + j][wc] = make_float2(lm, ls);
            }
        }
        __syncthreads();
        if (t < BM) {
            float2 a = Ls[t / (BM / 2)][t % (BM / 2)][0];
            float2 b = Ls[t / (BM / 2)][t % (BM / 2)][1];
            float mm = fmaxf(a.x, b.x);
            float ss = a.y * __expf(a.x - mm) + b.y * __expf(b.x - mm);
            part[(size_t)ntile * MR + m0 + t] = make_float2(mm, ss);
        }
    } else if constexpr (EPI == 0) {
        unsigned short* C = (unsigned short*)Cv;
        #pragma unroll
        for (int mi = 0; mi < MI; ++mi) {
            int r0 = rowb + mi * 16;
            #pragma unroll
            for (int ni = 0; ni < NI; ++ni) {
                int col = colb + ni * 16;
                float b4 = bias[col];
                float vals[4];
                #pragma unroll
                for (int j = 0; j < 4; ++j) vals[j] = acc[mi][ni][j] + b4;
                #pragma unroll
                for (int j = 0; j < 4; ++j)
                    C[(size_t)(r0 + j) * N + col] = f2b(vals[j]);
                if (col >= 2 * E) {   // V columns -> transposed side-copy
                    int d = col - 2 * E; int hh = d >> 6; d &= 63;
                    int bb2 = r0 >> 10, kv = r0 & (SQ - 1);
                    unsigned int lo = (unsigned int)f2b(vals[0]) | ((unsigned int)f2b(vals[1]) << 16);
                    unsigned int hi = (unsigned int)f2b(vals[2]) | ((unsigned int)f2b(vals[3]) << 16);
                    uint2 u; u.x = lo; u.y = hi;
                    *(uint2*)&vt[(((size_t)bb2 * NH + hh) * 64 + d) * SQ + kv] = u;
                }
            }
        }
    } else {
        #pragma unroll
        for (int mi = 0; mi < MI; ++mi) {
            #pragma unroll
            for (int ni = 0; ni < NI; ++ni) {
                int col = colb + ni * 16;
                #pragma unroll
                for (int j = 0; j < 4; ++j) {
                    int row = rowb + mi * 16 + j;
                    float v = acc[mi][ni][j] + bias[col];
                    if constexpr (EPI == 1) {
                        ((float*)Cv)[(size_t)row * N + col] =
                            v + resid[(size_t)row * N + col];
                    } else {
                        // tanh-approx GELU via sigmoid: v * sigmoid(1.5957691*(v+0.044715 v^3))
                        float u = v + 0.044715f * v * v * v;
                        float e = __expf(-1.5957691216f * u);
                        v = v / (1.f + e);
                        ((unsigned short*)Cv)[(size_t)row * N + col] = f2b(v);
                    }
                }
            }
        }
    }
}

// ---------------- MFMA flash attention (dbuf K/V, one barrier/tile, T5 setprio) ----------------
__global__ __launch_bounds__(256)
void attn_k(const unsigned short* __restrict__ qkv, const unsigned short* __restrict__ vtg,
            unsigned short* __restrict__ y)
{
    const int bid = blockIdx.x;
    const int qb  = (SQ / 64 - 1) - (bid / 48);
    const int bh  = bid % 48;
    const int h = bh % NH, b = bh / NH;
    const int t = threadIdx.x, lane = t & 63, wid = t >> 6;
    const int q0 = qb * 64;
    const int lq = lane & 15, lg = lane >> 4;

    __shared__ __align__(16) unsigned short Ks[2][64 * 72];
    __shared__ __align__(16) unsigned short Vs[2][64 * 72];
    __shared__ __align__(16) unsigned short Ps[4][16 * 72];

    const unsigned short* base  = qkv + (size_t)b * SQ * 2304;
    const unsigned short* vbase = vtg + (size_t)bh * 64 * SQ;

    const int qrow = q0 + wid * 16 + lq;
    bf16x8 qf0 = *(const bf16x8*)(base + (size_t)qrow * 2304 + h * 64 + lg * 8);
    bf16x8 qf1 = *(const bf16x8*)(base + (size_t)qrow * 2304 + h * 64 + 32 + lg * 8);

    const int sr = t >> 3, sc = t & 7;
    us8 ka, kb, va, vb;
    {
        const unsigned short* kp = base + (size_t)sr * 2304 + 768 + h * 64 + sc * 8;
        ka = *(const us8*)kp;
        kb = *(const us8*)(kp + (size_t)32 * 2304);
        const unsigned short* vp = vbase + (size_t)sr * SQ + sc * 8;
        va = *(const us8*)vp;
        vb = *(const us8*)(vp + (size_t)32 * SQ);
    }
    *(us8*)&Ks[0][sr * 72 + sc * 8] = ka;
    *(us8*)&Ks[0][(sr + 32) * 72 + sc * 8] = kb;
    *(us8*)&Vs[0][sr * 72 + sc * 8] = va;
    *(us8*)&Vs[0][(sr + 32) * 72 + sc * 8] = vb;
    __syncthreads();

    f32x4 of[4];
    const f32x4 fz = {0.f, 0.f, 0.f, 0.f};
    #pragma unroll
    for (int i = 0; i < 4; ++i) of[i] = fz;
    float mreg = -1e30f, lreg = 0.f;

    int cur = 0;
    for (int tt = 0; tt <= qb; ++tt) {
        if (tt < qb) {
            int kv0n = (tt + 1) * 64;
            const unsigned short* kp = base + (size_t)(kv0n + sr) * 2304 + 768 + h * 64 + sc * 8;
            ka = *(const us8*)kp;
            kb = *(const us8*)(kp + (size_t)32 * 2304);
            const unsigned short* vp = vbase + (size_t)sr * SQ + kv0n + sc * 8;
            va = *(const us8*)vp;
            vb = *(const us8*)(vp + (size_t)32 * SQ);
        }
        const unsigned short* Ksc = Ks[cur];
        const unsigned short* Vsc = Vs[cur];

        f32x4 sf[4];
        #pragma unroll
        for (int mi = 0; mi < 4; ++mi) sf[mi] = fz;
        __builtin_amdgcn_s_setprio(1);
        #pragma unroll
        for (int mi = 0; mi < 4; ++mi) {
            const unsigned short* kr = &Ksc[(mi * 16 + lq) * 72 + lg * 8];
            bf16x8 k0 = *(const bf16x8*)kr;
            bf16x8 k1 = *(const bf16x8*)(kr + 32);
            sf[mi] = __builtin_amdgcn_mfma_f32_16x16x32_bf16(k0, qf0, sf[mi], 0, 0, 0);
            sf[mi] = __builtin_amdgcn_mfma_f32_16x16x32_bf16(k1, qf1, sf[mi], 0, 0, 0);
        }
        __builtin_amdgcn_s_setprio(0);

        float pv[16];
        const int kvb = tt * 64 + lg * 4;
        #pragma unroll
        for (int mi = 0; mi < 4; ++mi)
            #pragma unroll
            for (int j = 0; j < 4; ++j) {
                float s = sf[mi][j] * 0.125f;
                if (tt == qb && (kvb + mi * 16 + j) > qrow) s = -1e30f;
                pv[mi * 4 + j] = s;
            }
        float tm = pv[0];
        #pragma unroll
        for (int i = 1; i < 16; ++i) tm = fmaxf(tm, pv[i]);
        tm = fmaxf(tm, __shfl_xor(tm, 16));
        tm = fmaxf(tm, __shfl_xor(tm, 32));
        float mn  = fmaxf(mreg, tm);
        float fac = __expf(mreg - mn);
        float ts = 0.f;
        #pragma unroll
        for (int i = 0; i < 16; ++i) { float p = __expf(pv[i] - mn); pv[i] = p; ts += p; }
        ts += __shfl_xor(ts, 16);
        ts += __shfl_xor(ts, 32);
        lreg = lreg * fac + ts;
        mreg = mn;
        #pragma unroll
        for (int j = 0; j < 4; ++j) {
            float fj = __shfl(fac, 20 * lg + j);
            of[0][j] *= fj; of[1][j] *= fj; of[2][j] *= fj; of[3][j] *= fj;
        }
        unsigned short* pw = &Ps[wid][lq * 72];
        #pragma unroll
        for (int mi = 0; mi < 4; ++mi) {
            unsigned int lo = (unsigned int)f2b(pv[mi * 4 + 0]) | ((unsigned int)f2b(pv[mi * 4 + 1]) << 16);
            unsigned int hi = (unsigned int)f2b(pv[mi * 4 + 2]) | ((unsigned int)f2b(pv[mi * 4 + 3]) << 16);
            uint2 u; u.x = lo; u.y = hi;
            *(uint2*)&pw[mi * 16 + lg * 4] = u;
        }
        __builtin_amdgcn_s_setprio(1);
        #pragma unroll
        for (int ks = 0; ks < 2; ++ks) {
            bf16x8 pf = *(const bf16x8*)&Ps[wid][lq * 72 + ks * 32 + lg * 8];
            #pragma unroll
            for (int ni = 0; ni < 4; ++ni) {
                bf16x8 vf = *(const bf16x8*)&Vsc[(ni * 16 + lq) * 72 + ks * 32 + lg * 8];
                of[ni] = __builtin_amdgcn_mfma_f32_16x16x32_bf16(pf, vf, of[ni], 0, 0, 0);
            }
        }
        __builtin_amdgcn_s_setprio(0);
        if (tt < qb) {
            int nb = cur ^ 1;
            *(us8*)&Ks[nb][sr * 72 + sc * 8] = ka;
            *(us8*)&Ks[nb][(sr + 32) * 72 + sc * 8] = kb;
            *(us8*)&Vs[nb][sr * 72 + sc * 8] = va;
            *(us8*)&Vs[nb][(sr + 32) * 72 + sc * 8] = vb;
        }
        __syncthreads();
        cur ^= 1;
    }

    float inv = 1.f / lreg;
    #pragma unroll
    for (int j = 0; j < 4; ++j) {
        float fj = __shfl(inv, 20 * lg + j);
        int row = q0 + wid * 16 + lg * 4 + j;
        unsigned short* yr = y + ((size_t)b * SQ + row) * E + h * 64 + lq;
        #pragma unroll
        for (int ni = 0; ni < 4; ++ni)
            yr[ni * 16] = f2b(of[ni][j] * fj);
    }
}

// ---------------- loss: merge per-tile partials, one wave per row ----------------
__global__ __launch_bounds__(256)
void lossred_k(const float2* __restrict__ part, const float* __restrict__ logits,
               const int* __restrict__ tgt, float* __restrict__ rl, int NT)
{
    int t = threadIdx.x, lane = t & 63, wid = t >> 6;
    int r = blockIdx.x * 4 + wid;
    float m = -1e30f, s = 0.f;
    for (int nt = lane; nt < NT; nt += 64) {
        float2 p = part[(size_t)nt * MR + r];
        float mm = fmaxf(m, p.x);
        s = s * __expf(m - mm) + p.y * __expf(p.x - mm);
        m = mm;
    }
    #pragma unroll
    for (int o = 1; o < 64; o <<= 1) {
        float m2 = __shfl_xor(m, o), s2 = __shfl_xor(s, o);
        float mm = fmaxf(m, m2);
        s = s * __expf(m - mm) + s2 * __expf(m2 - mm);
        m = mm;
    }
    if (lane == 0)
        rl[r] = __logf(s) + m - logits[(size_t)r * V + tgt[r]];
}

__global__ __launch_bounds__(256)
void finloss_k(const float* __restrict__ rl, float* __restrict__ out)
{
    __shared__ float red[256];
    int t = threadIdx.x;
    float s = 0.f;
    for (int i = t; i < MR; i += 256) s += rl[i];
    red[t] = s; __syncthreads();
    for (int o = 128; o > 0; o >>= 1) { if (t < o) red[t] += red[t + o]; __syncthreads(); }
    if (t == 0) out[0] = red[0] * (1.f / MR);
}

// ---------------- launch ----------------
extern "C" void kernel_launch(void* const* d_in, const int* in_sizes, int n_in,
                              void* d_out, int out_size, void* d_ws, size_t ws_size,
                              hipStream_t stream)
{
    const int*   idx    = (const int*)  d_in[0];
    const int*   tgt    = (const int*)  d_in[1];
    const float* wte    = (const float*)d_in[2];
    const float* wpe    = (const float*)d_in[3];
    const float* ln1_g  = (const float*)d_in[4];
    const float* ln1_b  = (const float*)d_in[5];
    const float* attn_w = (const float*)d_in[6];
    const float* attn_b = (const float*)d_in[7];
    const float* proj_w = (const float*)d_in[8];
    const float* proj_b = (const float*)d_in[9];
    const float* ln2_g  = (const float*)d_in[10];
    const float* ln2_b  = (const float*)d_in[11];
    const float* fc_w   = (const float*)d_in[12];
    const float* fc_b   = (const float*)d_in[13];
    const float* fcp_w  = (const float*)d_in[14];
    const float* fcp_b  = (const float*)d_in[15];
    const float* lnf_g  = (const float*)d_in[16];
    const float* lnf_b  = (const float*)d_in[17];

    unsigned char* p = (unsigned char*)d_ws;
    auto alloc = [&](size_t bytes) {
        unsigned char* r = p; p += (bytes + 255) & ~(size_t)255; return r;
    };
    float*          x    = (float*)         alloc((size_t)MR * E * 4);
    unsigned short* h    = (unsigned short*)alloc((size_t)MR * E * 2);
    unsigned short* qkv  = (unsigned short*)alloc((size_t)MR * 3 * E * 2);
    unsigned short* yb   = (unsigned short*)alloc((size_t)MR * E * 2);
    unsigned short* act  = (unsigned short*)alloc((size_t)MR * 4 * E * 2);
    unsigned short* wteb = (unsigned short*)alloc((size_t)V * E * 2);
    unsigned short* vtg  = (unsigned short*)alloc((size_t)NB * NH * 64 * SQ * 2);
    float2*         part = (float2*)        alloc((size_t)197 * MR * 8);
    float*          rl   = (float*)         alloc((size_t)MR * 4);

    size_t used = (size_t)(p - (unsigned char*)d_ws);
    size_t perL = (size_t)12 * E * E * 2 + 4 * 256;
    int NLW = (ws_size >= used + (size_t)NL * perL) ? NL : 1;
    unsigned short* wqA  = (unsigned short*)alloc((size_t)NLW * 3 * E * E * 2);
    unsigned short* wpA  = (unsigned short*)alloc((size_t)NLW * E * E * 2);
    unsigned short* wfA  = (unsigned short*)alloc((size_t)NLW * 4 * E * E * 2);
    unsigned short* wfpA = (unsigned short*)alloc((size_t)NLW * 4 * E * E * 2);

    float* logits = (float*)d_out;
    float* lossp  = logits + (size_t)MR * V;

    embed_k<<<MR, 256, 0, stream>>>(idx, wte, wpe, x);
    conv_k<<<2048, 256, 0, stream>>>(wte, wteb, (int)((size_t)V * E / 4));

    if (NLW == NL) {
        tconv_k<<<dim3(3 * E / 32, E / 32, NL), 256, 0, stream>>>(attn_w, wqA, E, 3 * E);
        tconv_k<<<dim3(E / 32, E / 32, NL), 256, 0, stream>>>(proj_w, wpA, E, E);
        tconv_k<<<dim3(4 * E / 32, E / 32, NL), 256, 0, stream>>>(fc_w, wfA, E, 4 * E);
        tconv_k<<<dim3(E / 32, 4 * E / 32, NL), 256, 0, stream>>>(fcp_w, wfpA, 4 * E, E);
    }

    for (int l = 0; l < NL; ++l) {
        int lw = (NLW == NL) ? l : 0;
        unsigned short* wq  = wqA  + (size_t)lw * 3 * E * E;
        unsigned short* wp  = wpA  + (size_t)lw * E * E;
        unsigned short* wf  = wfA  + (size_t)lw * 4 * E * E;
        unsigned short* wfp = wfpA + (size_t)lw * 4 * E * E;
        if (NLW != NL) {
            tconv_k<<<dim3(3 * E / 32, E / 32), 256, 0, stream>>>(
                attn_w + (size_t)l * E * 3 * E, wq, E, 3 * E);
            tconv_k<<<dim3(E / 32, E / 32), 256, 0, stream>>>(
                proj_w + (size_t)l * E * E, wp, E, E);
            tconv_k<<<dim3(4 * E / 32, E / 32), 256, 0, stream>>>(
                fc_w + (size_t)l * E * 4 * E, wf, E, 4 * E);
            tconv_k<<<dim3(E / 32, 4 * E / 32), 256, 0, stream>>>(
                fcp_w + (size_t)l * 4 * E * E, wfp, 4 * E, E);
        }

        ln_k<<<MR, 256, 0, stream>>>(x, ln1_g + l * E, ln1_b + l * E, h);
        gemm_k<0, false, 4, 4, 3><<<dim3(32, 18), 256, 0, stream>>>(
            h, wq, attn_b + (size_t)l * 3 * E, nullptr, qkv, vtg, nullptr,
            MR, 3 * E, E, 3 * E);
        attn_k<<<768, 256, 0, stream>>>(qkv, vtg, yb);
        gemm_k<1, false, 2, 4, 3><<<dim3(64, 6), 256, 0, stream>>>(
            yb, wp, proj_b + (size_t)l * E, x, x, nullptr, nullptr, MR, E, E, E);
        ln_k<<<MR, 256, 0, stream>>>(x, ln2_g + l * E, ln2_b + l * E, h);
        gemm_k<2, false, 4, 4, 3><<<dim3(32, 24), 256, 0, stream>>>(
            h, wf, fc_b + (size_t)l * 4 * E, nullptr, act, nullptr, nullptr,
            MR, 4 * E, E, 4 * E);
        gemm_k<1, false, 2, 4, 3><<<dim3(64, 6), 256, 0, stream>>>(
            act, wfp, fcp_b + (size_t)l * E, x, x, nullptr, nullptr, MR, E, 4 * E, E);
    }

    ln_k<<<MR, 256, 0, stream>>>(x, lnf_g, lnf_b, h);
    gemm_k<3, false, 4, 8, 2><<<dim3(32, 197), 256, 0, stream>>>(
        h, wteb, nullptr, nullptr, logits, nullptr, part, MR, 50304, E, V);

    lossred_k<<<MR / 4, 256, 0, stream>>>(part, logits, tgt, rl, 197);
    finloss_k<<<1, 256, 0, stream>>>(rl, lossp);
}

// Round 17
// 2603.126 us; speedup vs baseline: 1.0301x; 1.0301x over previous
//
#include <hip/hip_runtime.h>
#include <hip/hip_bf16.h>
#include <math.h>

#define V 50257
#define SQ 1024
#define E 768
#define NH 12
#define NL 12
#define NB 4
#define MR (NB*SQ)   // 4096 rows

typedef __bf16 bf16x8 __attribute__((ext_vector_type(8)));
typedef float f32x4 __attribute__((ext_vector_type(4)));
typedef unsigned short us8 __attribute__((ext_vector_type(8)));

__device__ __forceinline__ float b2f(unsigned short u) {
    union { float f; unsigned int i; } x; x.i = ((unsigned int)u) << 16; return x.f;
}
__device__ __forceinline__ unsigned short f2b(float f) {
    unsigned int u = __float_as_uint(f);
    u = (u + 0x7fff + ((u >> 16) & 1)) >> 16;   // RNE, finite inputs
    return (unsigned short)u;
}
__device__ __forceinline__ void gload16(const unsigned short* g, unsigned short* l) {
    __builtin_amdgcn_global_load_lds((const __attribute__((address_space(1))) void*)g,
                                     (__attribute__((address_space(3))) void*)l, 16, 0, 0);
}

// ---------------- embedding (fp32 out) ----------------
__global__ __launch_bounds__(256)
void embed_k(const int* __restrict__ idx, const float* __restrict__ wte,
             const float* __restrict__ wpe, float* __restrict__ x)
{
    int r = blockIdx.x, t = threadIdx.x;
    int tok = idx[r];
    int s = r & (SQ - 1);
    const float* wt = wte + (size_t)tok * E;
    const float* wp = wpe + (size_t)s * E;
    float* xr = x + (size_t)r * E;
    for (int e = t; e < E; e += 256) xr[e] = wt[e] + wp[e];
}

// ---------------- layernorm: fp32 in, bf16 out (r13 measured-best version) ----------------
__global__ __launch_bounds__(256)
void ln_k(const float* __restrict__ x, const float* __restrict__ g,
          const float* __restrict__ bb, unsigned short* __restrict__ out)
{
    int r = blockIdx.x, t = threadIdx.x;
    int lane = t & 63, wid = t >> 6;
    const float* xr = x + (size_t)r * E;
    float v0 = xr[t], v1 = xr[t + 256], v2 = xr[t + 512];
    float s = v0 + v1 + v2;
    #pragma unroll
    for (int o = 1; o < 64; o <<= 1) s += __shfl_xor(s, o);
    __shared__ float red[8];
    if (lane == 0) red[wid] = s;
    __syncthreads();
    float mu = (red[0] + red[1] + red[2] + red[3]) * (1.f / E);
    float d0 = v0 - mu, d1 = v1 - mu, d2 = v2 - mu;
    float s2 = d0 * d0 + d1 * d1 + d2 * d2;
    #pragma unroll
    for (int o = 1; o < 64; o <<= 1) s2 += __shfl_xor(s2, o);
    if (lane == 0) red[wid + 4] = s2;
    __syncthreads();
    float rs = rsqrtf((red[4] + red[5] + red[6] + red[7]) * (1.f / E) + 1e-5f);
    unsigned short* orow = out + (size_t)r * E;
    orow[t]       = f2b(d0 * rs * g[t] + bb[t]);
    orow[t + 256] = f2b(d1 * rs * g[t + 256] + bb[t + 256]);
    orow[t + 512] = f2b(d2 * rs * g[t + 512] + bb[t + 512]);
}

// ---------------- fp32 -> bf16 elementwise (wte) ----------------
__global__ __launch_bounds__(256)
void conv_k(const float* __restrict__ in, unsigned short* __restrict__ out, int n4)
{
    int i = blockIdx.x * 256 + threadIdx.x;
    int stride = gridDim.x * 256;
    for (; i < n4; i += stride) {
        float4 v = ((const float4*)in)[i];
        ushort4 o;
        o.x = f2b(v.x); o.y = f2b(v.y); o.z = f2b(v.z); o.w = f2b(v.w);
        ((ushort4*)out)[i] = o;
    }
}

// ---------------- transpose+convert: in [Kd,Nd] fp32 -> out [Nd,Kd] bf16 ----------------
__global__ __launch_bounds__(256)
void tconv_k(const float* __restrict__ in, unsigned short* __restrict__ out, int Kd, int Nd)
{
    __shared__ float tile[32][33];
    size_t loff = (size_t)blockIdx.z * Kd * Nd;
    in  += loff;
    out += loff;
    int n0 = blockIdx.x * 32, k0 = blockIdx.y * 32;
    int tc = threadIdx.x & 31, tr = threadIdx.x >> 5;
    #pragma unroll
    for (int i = 0; i < 4; ++i)
        tile[tr + i * 8][tc] = in[(size_t)(k0 + tr + i * 8) * Nd + n0 + tc];
    __syncthreads();
    #pragma unroll
    for (int i = 0; i < 4; ++i)
        out[(size_t)(n0 + tr + i * 8) * Kd + k0 + tc] = f2b(tile[tc][tr + i * 8]);
}

// ---------------- bf16 MFMA GEMM: C = epi(A @ B^T) ----------------
// Per-site configs A/B-measured (r6-r16): single-buffer everywhere.
// 128x128 qkv/fc (keep >=2 blocks/CU resident); 64x128 proj/fcp; 128x256 lm_head only.
// EPI: 0 bias->bf16 (+V-transpose side-write) | 1 bias+resid->fp32 | 2 bias+gelu->bf16
//      | 3 plain->fp32 N-guarded + online-softmax row partials (lm_head)
template<int EPI, bool DB, int MI, int NI, int MINW>
__global__ __launch_bounds__(256, MINW)
void gemm_k(const unsigned short* __restrict__ A, const unsigned short* __restrict__ B,
            const float* __restrict__ bias, const float* __restrict__ resid,
            void* __restrict__ Cv, unsigned short* __restrict__ vt,
            float2* __restrict__ part, int M, int N, int K, int Nreal)
{
    constexpr int NBUF = DB ? 2 : 1;
    constexpr int BM = 32 * MI, BN = 32 * NI;
    __shared__ __align__(16) unsigned short As[NBUF][BM * 64];
    __shared__ __align__(16) unsigned short Bs[NBUF][BN * 64];
    const int t = threadIdx.x;
    const int lane = t & 63, wv = t >> 6;
    const int wr = wv >> 1, wc = wv & 1;
    const int m0 = blockIdx.x * BM, n0 = blockIdx.y * BN;
    const int ntile = blockIdx.y;
    const int lq = lane & 15, lg = lane >> 4;

    f32x4 acc[MI][NI];
    const f32x4 fz = {0.f, 0.f, 0.f, 0.f};
    #pragma unroll
    for (int i = 0; i < MI; ++i)
        #pragma unroll
        for (int j = 0; j < NI; ++j) acc[i][j] = fz;

    const int srow = t >> 3, sc = t & 7;       // staging: 8 lanes/row, 16B chunks

    auto stage = [&](int buf, int k0) {
        #pragma unroll
        for (int i = 0; i < MI; ++i) {
            int row = srow + i * 32;
            int gc = ((sc ^ (row & 7)) << 3);           // pre-swizzled global chunk
            gload16(A + (size_t)(m0 + row) * K + k0 + gc, &As[buf][row * 64 + sc * 8]);
        }
        #pragma unroll
        for (int i = 0; i < NI; ++i) {
            int row = srow + i * 32;
            int gc = ((sc ^ (row & 7)) << 3);
            int nrow = n0 + row;
            if (EPI == 3 && nrow >= Nreal) nrow = Nreal - 1;
            gload16(B + (size_t)nrow * K + k0 + gc, &Bs[buf][row * 64 + sc * 8]);
        }
    };
    auto compute = [&](int buf) {
        #pragma unroll
        for (int ks = 0; ks < 64; ks += 32) {
            bf16x8 af[MI], bfr[NI];
            #pragma unroll
            for (int mi = 0; mi < MI; ++mi) {
                int row = wr * (16 * MI) + mi * 16 + lq;
                int c = (ks >> 3) + lg;
                af[mi] = *(const bf16x8*)&As[buf][row * 64 + ((c ^ (row & 7)) << 3)];
            }
            #pragma unroll
            for (int ni = 0; ni < NI; ++ni) {
                int row = wc * (16 * NI) + ni * 16 + lq;
                int c = (ks >> 3) + lg;
                bfr[ni] = *(const bf16x8*)&Bs[buf][row * 64 + ((c ^ (row & 7)) << 3)];
            }
            #pragma unroll
            for (int mi = 0; mi < MI; ++mi)
                #pragma unroll
                for (int ni = 0; ni < NI; ++ni)
                    acc[mi][ni] = __builtin_amdgcn_mfma_f32_16x16x32_bf16(
                        af[mi], bfr[ni], acc[mi][ni], 0, 0, 0);
        }
    };

    const int KT = K >> 6;
    if constexpr (DB) {
        stage(0, 0);
        __syncthreads();
        int cur = 0;
        for (int kt = 0; kt < KT; ++kt) {
            if (kt + 1 < KT) stage(cur ^ 1, (kt + 1) << 6);   // prefetch next tile
            compute(cur);
            __syncthreads();   // drains next-tile loads (overlapped with MFMA above)
            cur ^= 1;
        }
    } else {
        for (int kt = 0; kt < KT; ++kt) {
            stage(0, kt << 6);
            __syncthreads();
            compute(0);
            __syncthreads();
        }
    }

    // epilogue: D row=4*lg+j (+16mi +wr*16MI), col=lq (+16ni +wc*16NI)
    const int colb = n0 + wc * (16 * NI) + lq;
    const int rowb = m0 + wr * (16 * MI) + lg * 4;

    if constexpr (EPI == 3) {
        __shared__ float2 Ls[2][BM / 2][2];
        float* C = (float*)Cv;
        #pragma unroll
        for (int mi = 0; mi < MI; ++mi) {
            #pragma unroll
            for (int j = 0; j < 4; ++j) {
                int row = rowb + mi * 16 + j;
                float v[NI];
                #pragma unroll
                for (int ni = 0; ni < NI; ++ni) {
                    int col = colb + ni * 16;
                    float vv = acc[mi][ni][j];
                    if (col < Nreal) C[(size_t)row * Nreal + col] = vv;
                    else vv = -1e30f;
                    v[ni] = vv;
                }
                float lm = v[0];
                #pragma unroll
                for (int ni = 1; ni < NI; ++ni) lm = fmaxf(lm, v[ni]);
                #pragma unroll
                for (int o = 1; o < 16; o <<= 1) lm = fmaxf(lm, __shfl_xor(lm, o));
                float ls = 0.f;
                #pragma unroll
                for (int ni = 0; ni < NI; ++ni) ls += __expf(v[ni] - lm);
                #pragma unroll
                for (int o = 1; o < 16; o <<= 1) ls += __shfl_xor(ls, o);
                if (lq == 0) Ls[wr][mi * 16 + lg * 4 + j][wc] = make_float2(lm, ls);
            }
        }
        __syncthreads();
        if (t < BM) {
            float2 a = Ls[t / (BM / 2)][t % (BM / 2)][0];
            float2 b = Ls[t / (BM / 2)][t % (BM / 2)][1];
            float mm = fmaxf(a.x, b.x);
            float ss = a.y * __expf(a.x - mm) + b.y * __expf(b.x - mm);
            part[(size_t)ntile * MR + m0 + t] = make_float2(mm, ss);
        }
    } else if constexpr (EPI == 0) {
        unsigned short* C = (unsigned short*)Cv;
        #pragma unroll
        for (int mi = 0; mi < MI; ++mi) {
            int r0 = rowb + mi * 16;
            #pragma unroll
            for (int ni = 0; ni < NI; ++ni) {
                int col = colb + ni * 16;
                float b4 = bias[col];
                float vals[4];
                #pragma unroll
                for (int j = 0; j < 4; ++j) vals[j] = acc[mi][ni][j] + b4;
                #pragma unroll
                for (int j = 0; j < 4; ++j)
                    C[(size_t)(r0 + j) * N + col] = f2b(vals[j]);
                if (col >= 2 * E) {   // V columns -> transposed side-copy
                    int d = col - 2 * E; int hh = d >> 6; d &= 63;
                    int bb2 = r0 >> 10, kv = r0 & (SQ - 1);
                    unsigned int lo = (unsigned int)f2b(vals[0]) | ((unsigned int)f2b(vals[1]) << 16);
                    unsigned int hi = (unsigned int)f2b(vals[2]) | ((unsigned int)f2b(vals[3]) << 16);
                    uint2 u; u.x = lo; u.y = hi;
                    *(uint2*)&vt[(((size_t)bb2 * NH + hh) * 64 + d) * SQ + kv] = u;
                }
            }
        }
    } else {
        #pragma unroll
        for (int mi = 0; mi < MI; ++mi) {
            #pragma unroll
            for (int ni = 0; ni < NI; ++ni) {
                int col = colb + ni * 16;
                #pragma unroll
                for (int j = 0; j < 4; ++j) {
                    int row = rowb + mi * 16 + j;
                    float v = acc[mi][ni][j] + bias[col];
                    if constexpr (EPI == 1) {
                        ((float*)Cv)[(size_t)row * N + col] =
                            v + resid[(size_t)row * N + col];
                    } else {
                        // tanh-approx GELU via sigmoid: v * sigmoid(1.5957691*(v+0.044715 v^3))
                        float u = v + 0.044715f * v * v * v;
                        float e = __expf(-1.5957691216f * u);
                        v = v / (1.f + e);
                        ((unsigned short*)Cv)[(size_t)row * N + col] = f2b(v);
                    }
                }
            }
        }
    }
}

// ---------------- MFMA flash attention (dbuf K/V, one barrier/tile) ----------------
__global__ __launch_bounds__(256)
void attn_k(const unsigned short* __restrict__ qkv, const unsigned short* __restrict__ vtg,
            unsigned short* __restrict__ y)
{
    const int bid = blockIdx.x;
    const int qb  = (SQ / 64 - 1) - (bid / 48);
    const int bh  = bid % 48;
    const int h = bh % NH, b = bh / NH;
    const int t = threadIdx.x, lane = t & 63, wid = t >> 6;
    const int q0 = qb * 64;
    const int lq = lane & 15, lg = lane >> 4;

    __shared__ __align__(16) unsigned short Ks[2][64 * 72];
    __shared__ __align__(16) unsigned short Vs[2][64 * 72];
    __shared__ __align__(16) unsigned short Ps[4][16 * 72];

    const unsigned short* base  = qkv + (size_t)b * SQ * 2304;
    const unsigned short* vbase = vtg + (size_t)bh * 64 * SQ;

    const int qrow = q0 + wid * 16 + lq;
    bf16x8 qf0 = *(const bf16x8*)(base + (size_t)qrow * 2304 + h * 64 + lg * 8);
    bf16x8 qf1 = *(const bf16x8*)(base + (size_t)qrow * 2304 + h * 64 + 32 + lg * 8);

    const int sr = t >> 3, sc = t & 7;
    us8 ka, kb, va, vb;
    {
        const unsigned short* kp = base + (size_t)sr * 2304 + 768 + h * 64 + sc * 8;
        ka = *(const us8*)kp;
        kb = *(const us8*)(kp + (size_t)32 * 2304);
        const unsigned short* vp = vbase + (size_t)sr * SQ + sc * 8;
        va = *(const us8*)vp;
        vb = *(const us8*)(vp + (size_t)32 * SQ);
    }
    *(us8*)&Ks[0][sr * 72 + sc * 8] = ka;
    *(us8*)&Ks[0][(sr + 32) * 72 + sc * 8] = kb;
    *(us8*)&Vs[0][sr * 72 + sc * 8] = va;
    *(us8*)&Vs[0][(sr + 32) * 72 + sc * 8] = vb;
    __syncthreads();

    f32x4 of[4];
    const f32x4 fz = {0.f, 0.f, 0.f, 0.f};
    #pragma unroll
    for (int i = 0; i < 4; ++i) of[i] = fz;
    float mreg = -1e30f, lreg = 0.f;

    int cur = 0;
    for (int tt = 0; tt <= qb; ++tt) {
        if (tt < qb) {
            int kv0n = (tt + 1) * 64;
            const unsigned short* kp = base + (size_t)(kv0n + sr) * 2304 + 768 + h * 64 + sc * 8;
            ka = *(const us8*)kp;
            kb = *(const us8*)(kp + (size_t)32 * 2304);
            const unsigned short* vp = vbase + (size_t)sr * SQ + kv0n + sc * 8;
            va = *(const us8*)vp;
            vb = *(const us8*)(vp + (size_t)32 * SQ);
        }
        const unsigned short* Ksc = Ks[cur];
        const unsigned short* Vsc = Vs[cur];

        f32x4 sf[4];
        #pragma unroll
        for (int mi = 0; mi < 4; ++mi) sf[mi] = fz;
        #pragma unroll
        for (int mi = 0; mi < 4; ++mi) {
            const unsigned short* kr = &Ksc[(mi * 16 + lq) * 72 + lg * 8];
            bf16x8 k0 = *(const bf16x8*)kr;
            bf16x8 k1 = *(const bf16x8*)(kr + 32);
            sf[mi] = __builtin_amdgcn_mfma_f32_16x16x32_bf16(k0, qf0, sf[mi], 0, 0, 0);
            sf[mi] = __builtin_amdgcn_mfma_f32_16x16x32_bf16(k1, qf1, sf[mi], 0, 0, 0);
        }

        float pv[16];
        const int kvb = tt * 64 + lg * 4;
        #pragma unroll
        for (int mi = 0; mi < 4; ++mi)
            #pragma unroll
            for (int j = 0; j < 4; ++j) {
                float s = sf[mi][j] * 0.125f;
                if (tt == qb && (kvb + mi * 16 + j) > qrow) s = -1e30f;
                pv[mi * 4 + j] = s;
            }
        float tm = pv[0];
        #pragma unroll
        for (int i = 1; i < 16; ++i) tm = fmaxf(tm, pv[i]);
        tm = fmaxf(tm, __shfl_xor(tm, 16));
        tm = fmaxf(tm, __shfl_xor(tm, 32));
        float mn  = fmaxf(mreg, tm);
        float fac = __expf(mreg - mn);
        float ts = 0.f;
        #pragma unroll
        for (int i = 0; i < 16; ++i) { float p = __expf(pv[i] - mn); pv[i] = p; ts += p; }
        ts += __shfl_xor(ts, 16);
        ts += __shfl_xor(ts, 32);
        lreg = lreg * fac + ts;
        mreg = mn;
        #pragma unroll
        for (int j = 0; j < 4; ++j) {
            float fj = __shfl(fac, 20 * lg + j);
            of[0][j] *= fj; of[1][j] *= fj; of[2][j] *= fj; of[3][j] *= fj;
        }
        unsigned short* pw = &Ps[wid][lq * 72];
        #pragma unroll
        for (int mi = 0; mi < 4; ++mi) {
            unsigned int lo = (unsigned int)f2b(pv[mi * 4 + 0]) | ((unsigned int)f2b(pv[mi * 4 + 1]) << 16);
            unsigned int hi = (unsigned int)f2b(pv[mi * 4 + 2]) | ((unsigned int)f2b(pv[mi * 4 + 3]) << 16);
            uint2 u; u.x = lo; u.y = hi;
            *(uint2*)&pw[mi * 16 + lg * 4] = u;
        }
        #pragma unroll
        for (int ks = 0; ks < 2; ++ks) {
            bf16x8 pf = *(const bf16x8*)&Ps[wid][lq * 72 + ks * 32 + lg * 8];
            #pragma unroll
            for (int ni = 0; ni < 4; ++ni) {
                bf16x8 vf = *(const bf16x8*)&Vsc[(ni * 16 + lq) * 72 + ks * 32 + lg * 8];
                of[ni] = __builtin_amdgcn_mfma_f32_16x16x32_bf16(pf, vf, of[ni], 0, 0, 0);
            }
        }
        if (tt < qb) {
            int nb = cur ^ 1;
            *(us8*)&Ks[nb][sr * 72 + sc * 8] = ka;
            *(us8*)&Ks[nb][(sr + 32) * 72 + sc * 8] = kb;
            *(us8*)&Vs[nb][sr * 72 + sc * 8] = va;
            *(us8*)&Vs[nb][(sr + 32) * 72 + sc * 8] = vb;
        }
        __syncthreads();
        cur ^= 1;
    }

    float inv = 1.f / lreg;
    #pragma unroll
    for (int j = 0; j < 4; ++j) {
        float fj = __shfl(inv, 20 * lg + j);
        int row = q0 + wid * 16 + lg * 4 + j;
        unsigned short* yr = y + ((size_t)b * SQ + row) * E + h * 64 + lq;
        #pragma unroll
        for (int ni = 0; ni < 4; ++ni)
            yr[ni * 16] = f2b(of[ni][j] * fj);
    }
}

// ---------------- loss: merge per-tile partials, one wave per row ----------------
__global__ __launch_bounds__(256)
void lossred_k(const float2* __restrict__ part, const float* __restrict__ logits,
               const int* __restrict__ tgt, float* __restrict__ rl, int NT)
{
    int t = threadIdx.x, lane = t & 63, wid = t >> 6;
    int r = blockIdx.x * 4 + wid;
    float m = -1e30f, s = 0.f;
    for (int nt = lane; nt < NT; nt += 64) {
        float2 p = part[(size_t)nt * MR + r];
        float mm = fmaxf(m, p.x);
        s = s * __expf(m - mm) + p.y * __expf(p.x - mm);
        m = mm;
    }
    #pragma unroll
    for (int o = 1; o < 64; o <<= 1) {
        float m2 = __shfl_xor(m, o), s2 = __shfl_xor(s, o);
        float mm = fmaxf(m, m2);
        s = s * __expf(m - mm) + s2 * __expf(m2 - mm);
        m = mm;
    }
    if (lane == 0)
        rl[r] = __logf(s) + m - logits[(size_t)r * V + tgt[r]];
}

__global__ __launch_bounds__(256)
void finloss_k(const float* __restrict__ rl, float* __restrict__ out)
{
    __shared__ float red[256];
    int t = threadIdx.x;
    float s = 0.f;
    for (int i = t; i < MR; i += 256) s += rl[i];
    red[t] = s; __syncthreads();
    for (int o = 128; o > 0; o >>= 1) { if (t < o) red[t] += red[t + o]; __syncthreads(); }
    if (t == 0) out[0] = red[0] * (1.f / MR);
}

// ---------------- launch ----------------
extern "C" void kernel_launch(void* const* d_in, const int* in_sizes, int n_in,
                              void* d_out, int out_size, void* d_ws, size_t ws_size,
                              hipStream_t stream)
{
    const int*   idx    = (const int*)  d_in[0];
    const int*   tgt    = (const int*)  d_in[1];
    const float* wte    = (const float*)d_in[2];
    const float* wpe    = (const float*)d_in[3];
    const float* ln1_g  = (const float*)d_in[4];
    const float* ln1_b  = (const float*)d_in[5];
    const float* attn_w = (const float*)d_in[6];
    const float* attn_b = (const float*)d_in[7];
    const float* proj_w = (const float*)d_in[8];
    const float* proj_b = (const float*)d_in[9];
    const float* ln2_g  = (const float*)d_in[10];
    const float* ln2_b  = (const float*)d_in[11];
    const float* fc_w   = (const float*)d_in[12];
    const float* fc_b   = (const float*)d_in[13];
    const float* fcp_w  = (const float*)d_in[14];
    const float* fcp_b  = (const float*)d_in[15];
    const float* lnf_g  = (const float*)d_in[16];
    const float* lnf_b  = (const float*)d_in[17];

    unsigned char* p = (unsigned char*)d_ws;
    auto alloc = [&](size_t bytes) {
        unsigned char* r = p; p += (bytes + 255) & ~(size_t)255; return r;
    };
    float*          x    = (float*)         alloc((size_t)MR * E * 4);
    unsigned short* h    = (unsigned short*)alloc((size_t)MR * E * 2);
    unsigned short* qkv  = (unsigned short*)alloc((size_t)MR * 3 * E * 2);
    unsigned short* yb   = (unsigned short*)alloc((size_t)MR * E * 2);
    unsigned short* act  = (unsigned short*)alloc((size_t)MR * 4 * E * 2);
    unsigned short* wteb = (unsigned short*)alloc((size_t)V * E * 2);
    unsigned short* vtg  = (unsigned short*)alloc((size_t)NB * NH * 64 * SQ * 2);
    float2*         part = (float2*)        alloc((size_t)197 * MR * 8);
    float*          rl   = (float*)         alloc((size_t)MR * 4);

    size_t used = (size_t)(p - (unsigned char*)d_ws);
    size_t perL = (size_t)12 * E * E * 2 + 4 * 256;
    int NLW = (ws_size >= used + (size_t)NL * perL) ? NL : 1;
    unsigned short* wqA  = (unsigned short*)alloc((size_t)NLW * 3 * E * E * 2);
    unsigned short* wpA  = (unsigned short*)alloc((size_t)NLW * E * E * 2);
    unsigned short* wfA  = (unsigned short*)alloc((size_t)NLW * 4 * E * E * 2);
    unsigned short* wfpA = (unsigned short*)alloc((size_t)NLW * 4 * E * E * 2);

    float* logits = (float*)d_out;
    float* lossp  = logits + (size_t)MR * V;

    embed_k<<<MR, 256, 0, stream>>>(idx, wte, wpe, x);
    conv_k<<<2048, 256, 0, stream>>>(wte, wteb, (int)((size_t)V * E / 4));

    if (NLW == NL) {
        tconv_k<<<dim3(3 * E / 32, E / 32, NL), 256, 0, stream>>>(attn_w, wqA, E, 3 * E);
        tconv_k<<<dim3(E / 32, E / 32, NL), 256, 0, stream>>>(proj_w, wpA, E, E);
        tconv_k<<<dim3(4 * E / 32, E / 32, NL), 256, 0, stream>>>(fc_w, wfA, E, 4 * E);
        tconv_k<<<dim3(E / 32, 4 * E / 32, NL), 256, 0, stream>>>(fcp_w, wfpA, 4 * E, E);
    }

    for (int l = 0; l < NL; ++l) {
        int lw = (NLW == NL) ? l : 0;
        unsigned short* wq  = wqA  + (size_t)lw * 3 * E * E;
        unsigned short* wp  = wpA  + (size_t)lw * E * E;
        unsigned short* wf  = wfA  + (size_t)lw * 4 * E * E;
        unsigned short* wfp = wfpA + (size_t)lw * 4 * E * E;
        if (NLW != NL) {
            tconv_k<<<dim3(3 * E / 32, E / 32), 256, 0, stream>>>(
                attn_w + (size_t)l * E * 3 * E, wq, E, 3 * E);
            tconv_k<<<dim3(E / 32, E / 32), 256, 0, stream>>>(
                proj_w + (size_t)l * E * E, wp, E, E);
            tconv_k<<<dim3(4 * E / 32, E / 32), 256, 0, stream>>>(
                fc_w + (size_t)l * E * 4 * E, wf, E, 4 * E);
            tconv_k<<<dim3(E / 32, 4 * E / 32), 256, 0, stream>>>(
                fcp_w + (size_t)l * 4 * E * E, wfp, 4 * E, E);
        }

        ln_k<<<MR, 256, 0, stream>>>(x, ln1_g + l * E, ln1_b + l * E, h);
        gemm_k<0, false, 4, 4, 3><<<dim3(32, 18), 256, 0, stream>>>(
            h, wq, attn_b + (size_t)l * 3 * E, nullptr, qkv, vtg, nullptr,
            MR, 3 * E, E, 3 * E);
        attn_k<<<768, 256, 0, stream>>>(qkv, vtg, yb);
        gemm_k<1, false, 2, 4, 3><<<dim3(64, 6), 256, 0, stream>>>(
            yb, wp, proj_b + (size_t)l * E, x, x, nullptr, nullptr, MR, E, E, E);
        ln_k<<<MR, 256, 0, stream>>>(x, ln2_g + l * E, ln2_b + l * E, h);
        gemm_k<2, false, 4, 4, 3><<<dim3(32, 24), 256, 0, stream>>>(
            h, wf, fc_b + (size_t)l * 4 * E, nullptr, act, nullptr, nullptr,
            MR, 4 * E, E, 4 * E);
        gemm_k<1, false, 2, 4, 3><<<dim3(64, 6), 256, 0, stream>>>(
            act, wfp, fcp_b + (size_t)l * E, x, x, nullptr, nullptr, MR, E, 4 * E, E);
    }

    ln_k<<<MR, 256, 0, stream>>>(x, lnf_g, lnf_b, h);
    gemm_k<3, false, 4, 8, 2><<<dim3(32, 197), 256, 0, stream>>>(
        h, wteb, nullptr, nullptr, logits, nullptr, part, MR, 50304, E, V);

    lossred_k<<<MR / 4, 256, 0, stream>>>(part, logits, tgt, rl, 197);
    finloss_k<<<1, 256, 0, stream>>>(rl, lossp);
}